// Round 9
// baseline (194.755 us; speedup 1.0000x reference)
//
#include <hip/hip_runtime.h>
#include <stdint.h>

// MHA fused forward: qs@Wqkv -> flash attention (key mask) -> ctx@Wout + bout
// All matmuls via bf16 MFMA 16x16x32 (fp32 accumulate).

typedef unsigned short u16;
typedef uint32_t u32;
typedef u16   u16x4  __attribute__((ext_vector_type(4)));
typedef u16   u16x8  __attribute__((ext_vector_type(8)));
typedef __bf16 bf16x8 __attribute__((ext_vector_type(8)));
typedef float f32x4  __attribute__((ext_vector_type(4)));

#define DEV __device__ __forceinline__

DEV u16 cvt_bf(float f) {          // native f32->bf16 cast (1 VALU op)
    return __builtin_bit_cast(u16, (__bf16)f);
}

DEV void async16(const void* g, void* l) {   // 16B global->LDS direct (wave-uniform LDS base)
    __builtin_amdgcn_global_load_lds(
        reinterpret_cast<const uint32_t __attribute__((address_space(1)))*>(
            reinterpret_cast<uintptr_t>(g)),
        reinterpret_cast<uint32_t __attribute__((address_space(3)))*>(
            reinterpret_cast<uintptr_t>(l)),
        16, 0, 0);
}

DEV f32x4 mfma16(bf16x8 a, bf16x8 b, f32x4 c) {
    return __builtin_amdgcn_mfma_f32_16x16x32_bf16(a, b, c, 0, 0, 0);
}

// ------- prep (one launch): qs fp32->bf16, mask bias, both weight transposes -------

__global__ void k_prep(const float* __restrict__ qs, u16* __restrict__ qs_bf,
                       const int* __restrict__ m, float* __restrict__ bias,
                       const float* __restrict__ Wqkv, u16* __restrict__ WqkvT,
                       const float* __restrict__ Wout, u16* __restrict__ WoutT) {
    __shared__ float t[32][33];
    int bid = blockIdx.x;
    if (bid < 4096) {                       // qs convert: 4M elems
        int i = (bid * 256 + threadIdx.x) * 4;
        float4 v = *reinterpret_cast<const float4*>(qs + i);
        u16x4 o = { cvt_bf(v.x), cvt_bf(v.y), cvt_bf(v.z), cvt_bf(v.w) };
        *reinterpret_cast<u16x4*>(qs_bf + i) = o;
        return;
    }
    if (bid < 4112) {                       // mask -> additive bias
        int i = (bid - 4096) * 256 + threadIdx.x;
        bias[i] = m[i] ? 0.0f : -1.0e9f;
        return;
    }
    // weight transpose: dst[C x R] = bf16(src[R x C])^T
    const float* src; u16* dst; int R, C, bx, by;
    if (bid < 7184) { int q = bid - 4112; src = Wqkv; dst = WqkvT; R = 1024; C = 3072; bx = q % 96; by = q / 96; }
    else            { int q = bid - 7184; src = Wout; dst = WoutT; R = 1024; C = 1024; bx = q % 32; by = q / 32; }
    int c0 = bx * 32, r0 = by * 32;
    int tx = threadIdx.x & 31, ty = threadIdx.x >> 5;
#pragma unroll
    for (int i = 0; i < 4; ++i)
        t[ty + 8 * i][tx] = src[(size_t)(r0 + ty + 8 * i) * C + c0 + tx];
    __syncthreads();
#pragma unroll
    for (int i = 0; i < 4; ++i)
        dst[(size_t)(c0 + ty + 8 * i) * R + r0 + tx] = cvt_bf(t[tx][ty + 8 * i]);
}

// ---------------- GEMM: C[MxN] = A[MxK] @ Bt[NxK]^T (+bias) ----------------
// BM x BN tile, BK=32, 256 threads = 4 waves (2x2). Single-barrier double-buffered
// loop (unchanged from round 5/8 — held constant this round).

template <int BM, int BN, bool OUT_BF16, bool HAS_BIAS>
__global__ __launch_bounds__(256, 3) void k_gemm(
    const u16* __restrict__ A, const u16* __restrict__ Bt,
    void* __restrict__ Cv, const float* __restrict__ bias,
    int M, int N, int K)
{
    constexpr int MT = BM / 32, NT = BN / 32;         // frags per wave
    __shared__ __attribute__((aligned(16))) u16 As[2][BM * 32];
    __shared__ __attribute__((aligned(16))) u16 Bs[2][BN * 32];

    const int tid = threadIdx.x, wave = tid >> 6, lane = tid & 63;
    const int lh = lane & 15, lg = lane >> 4;
    const int nbn = N / BN;

    // bijective XCD swizzle
    const int nwg = gridDim.x;
    const int q8 = nwg >> 3, r8 = nwg & 7;
    const int xcd = blockIdx.x & 7, li = blockIdx.x >> 3;
    const int wg = (xcd < r8 ? xcd * (q8 + 1) : r8 * (q8 + 1) + (xcd - r8) * q8) + li;

    const int m0 = (wg / nbn) * BM, n0 = (wg % nbn) * BN;
    const int wm = wave >> 1, wn = wave & 1;          // 2 x 2 waves
    const int nk = K >> 5;

    auto stage = [&](int buf, int kt) {
#pragma unroll
        for (int i = 0; i < BM / 64; ++i) {           // A: BM*4 chunks of 16B
            int c = i * 256 + tid;
            int row = c >> 2, cc = c & 3;
            int sc = cc ^ (row & 3);                  // pre-swizzled global source
            async16(A + (size_t)(m0 + row) * K + kt * 32 + sc * 8, &As[buf][c * 8]);
        }
#pragma unroll
        for (int i = 0; i < BN / 64; ++i) {           // B: BN*4 chunks
            int c = i * 256 + tid;
            int row = c >> 2, cc = c & 3;
            int sc = cc ^ (row & 3);
            async16(Bt + (size_t)(n0 + row) * K + kt * 32 + sc * 8, &Bs[buf][c * 8]);
        }
    };

    f32x4 acc[MT][NT] = {};
    stage(0, 0);
    __syncthreads();                        // tile 0 landed (vmcnt drain at barrier)
    int buf = 0;
    for (int kt = 0; kt < nk; ++kt) {
        if (kt + 1 < nk) stage(buf ^ 1, kt + 1);
        bf16x8 af[MT], bf_[NT];
#pragma unroll
        for (int mt = 0; mt < MT; ++mt) {
            int row = wm * (BM / 2) + mt * 16 + lh;
            int off = row * 32 + ((lg ^ (row & 3)) * 8);           // u16 units
            af[mt] = __builtin_bit_cast(bf16x8,
                     *reinterpret_cast<const u16x8*>(&As[buf][off]));
        }
#pragma unroll
        for (int nt = 0; nt < NT; ++nt) {
            int row = wn * (BN / 2) + nt * 16 + lh;
            int off = row * 32 + ((lg ^ (row & 3)) * 8);
            bf_[nt] = __builtin_bit_cast(bf16x8,
                      *reinterpret_cast<const u16x8*>(&Bs[buf][off]));
        }
        __builtin_amdgcn_s_setprio(1);
#pragma unroll
        for (int mt = 0; mt < MT; ++mt)
#pragma unroll
            for (int nt = 0; nt < NT; ++nt)
                acc[mt][nt] = mfma16(af[mt], bf_[nt], acc[mt][nt]);
        __builtin_amdgcn_s_setprio(0);
        __syncthreads();                    // reads(buf) done; stage(kt+1) drained
        buf ^= 1;
    }

#pragma unroll
    for (int mt = 0; mt < MT; ++mt)
#pragma unroll
        for (int nt = 0; nt < NT; ++nt) {
            int col = n0 + wn * (BN / 2) + nt * 16 + lh;
#pragma unroll
            for (int r = 0; r < 4; ++r) {
                int row = m0 + wm * (BM / 2) + mt * 16 + 4 * lg + r;   // C/D: row=4*(l>>4)+r
                float v = acc[mt][nt][r];
                if (HAS_BIAS) v += bias[col];
                if (OUT_BF16) ((u16*)Cv)[(size_t)row * N + col] = cvt_bf(v);
                else          ((float*)Cv)[(size_t)row * N + col] = v;
            }
        }
}

// ---------------- flash attention: 4 waves x 32 q-rows (2 m-frags) ----------------
// qkv layout: ((b*2048+s)*48 + c)*64 + a ; c = h (Q), 16+h (K), 32+h (V)
// 512 blocks x 256 threads, 3 blocks/CU (LDS 53248B x 3 = 159.7KB). KBLK=64.
// DS-amortization: each kb/vb b128 read now feeds 2 MFMA (was 1 with 16-row waves)
// -> per-block b128 reads/tile drop 160->80. Same sync skeleton/swizzles as r5.

__global__ __launch_bounds__(256, 3) void k_attn(
    const u16* __restrict__ qkv, const float* __restrict__ biasg, u16* __restrict__ ctx)
{
    __shared__ __attribute__((aligned(16))) u16 Ks[2][64 * 64];   // row-major, src-swizzled chunks
    __shared__ __attribute__((aligned(16))) u16 Vt[2][64 * 72];   // [a][k], k XOR-swizzled by a-group
    __shared__ __attribute__((aligned(16))) u16 Ps[4 * 32 * 72];  // per-wave P (32 rows), stride 72

    const int tid = threadIdx.x, wave = tid >> 6, lane = tid & 63;
    const int lh = lane & 15, lg = lane >> 4;

    const int wg = (blockIdx.x & 7) * 64 + (blockIdx.x >> 3);     // XCD swizzle (512 = 8*64)
    const int qt = wg & 15, bh = wg >> 4;
    const int b = bh >> 4, h = bh & 15;

    const u16* qbase = qkv + ((size_t)b * 2048 * 48 + h) * 64;
    const u16* kbase = qkv + ((size_t)b * 2048 * 48 + 16 + h) * 64;
    const u16* vbase = qkv + ((size_t)b * 2048 * 48 + 32 + h) * 64;
    const float* brow = biasg + b * 2048;

    // staging geometry: thread handles chunks c = (wave*2+i)*64 + lane, i in {0,1}
    // (group base wave-uniform for global_load_lds; 512 chunks = 64 rows x 8)
    int srow_[2], scc_[2];
#pragma unroll
    for (int i = 0; i < 2; ++i) {
        int c = (wave * 2 + i) * 64 + lane;
        srow_[i] = c >> 3; scc_[i] = c & 7;
    }

    // Q fragments: rows qt*128 + wave*32 + mt*16 + lh ; d = ks*32 + lg*8 ..+7
    bf16x8 qf[2][2];
#pragma unroll
    for (int mt = 0; mt < 2; ++mt) {
        int row = qt * 128 + wave * 32 + mt * 16 + lh;
        qf[mt][0] = __builtin_bit_cast(bf16x8,
            *reinterpret_cast<const u16x8*>(qbase + (size_t)row * 3072 + lg * 8));
        qf[mt][1] = __builtin_bit_cast(bf16x8,
            *reinterpret_cast<const u16x8*>(qbase + (size_t)row * 3072 + 32 + lg * 8));
    }

    f32x4 oa[2][4] = {};
    float lst[2][4] = {};

    u16* Pw = &Ps[wave * 32 * 72];

    // prologue: stage tile 0 into buf 0
#pragma unroll
    for (int i = 0; i < 2; ++i) {
        int srow = srow_[i], scc = scc_[i];
        async16(kbase + (size_t)srow * 3072 + (scc ^ (srow & 7)) * 8, &Ks[0][(wave * 2 + i) * 512]);
        u16x8 v = *reinterpret_cast<const u16x8*>(vbase + (size_t)srow * 3072 + scc * 8);
#pragma unroll
        for (int j = 0; j < 8; ++j) Vt[0][(scc * 8 + j) * 72 + (srow ^ (scc << 3))] = v[j];
    }

    for (int kt = 0; kt < 32; ++kt) {
        __syncthreads();   // stage(kt) landed (vmcnt/lgkm drain); compute(kt-1) done
        const int buf = kt & 1;
        if (kt + 1 < 32) {
#pragma unroll
            for (int i = 0; i < 2; ++i) {
                int srow = srow_[i], scc = scc_[i];
                async16(kbase + (size_t)((kt + 1) * 64 + srow) * 3072 + (scc ^ (srow & 7)) * 8,
                        &Ks[buf ^ 1][(wave * 2 + i) * 512]);
                u16x8 v = *reinterpret_cast<const u16x8*>(
                    vbase + (size_t)((kt + 1) * 64 + srow) * 3072 + scc * 8);
#pragma unroll
                for (int j = 0; j < 8; ++j)
                    Vt[buf ^ 1][(scc * 8 + j) * 72 + (srow ^ (scc << 3))] = v[j];
            }
        }

        float biasv[4];
#pragma unroll
        for (int nt = 0; nt < 4; ++nt) biasv[nt] = brow[kt * 64 + nt * 16 + lh];

        // ---- S = Q K^T (per wave: 32 x 64); kb shared across both m-frags ----
        f32x4 sa[2][4] = {};
        __builtin_amdgcn_s_setprio(1);
#pragma unroll
        for (int ks = 0; ks < 2; ++ks) {
            bf16x8 kb[4];
#pragma unroll
            for (int nt = 0; nt < 4; ++nt) {
                int row = nt * 16 + lh;
                int off = row * 64 + (((ks * 4 + lg) ^ (row & 7)) << 3);   // u16 units
                kb[nt] = __builtin_bit_cast(bf16x8,
                         *reinterpret_cast<const u16x8*>(&Ks[buf][off]));
            }
#pragma unroll
            for (int mt = 0; mt < 2; ++mt)
#pragma unroll
                for (int nt = 0; nt < 4; ++nt)
                    sa[mt][nt] = mfma16(qf[mt][ks], kb[nt], sa[mt][nt]);
        }
        __builtin_amdgcn_s_setprio(0);

        // ---- no-max softmax: e = __expf(fma(s, 0.125, bias)) — native v_exp path ----
#pragma unroll
        for (int mt = 0; mt < 2; ++mt)
#pragma unroll
            for (int nt = 0; nt < 4; ++nt)
#pragma unroll
                for (int r = 0; r < 4; ++r) {
                    float e = __expf(fmaf(sa[mt][nt][r], 0.125f, biasv[nt]));
                    lst[mt][r] += e;
                    Pw[(mt * 16 + 4 * lg + r) * 72 + nt * 16 + lh] = cvt_bf(e);  // D-layout write
                }

        // ---- O += P V ; vb shared across both m-frags ----
        __builtin_amdgcn_s_setprio(1);
#pragma unroll
        for (int ks = 0; ks < 2; ++ks) {
            bf16x8 pa[2], vb[4];
#pragma unroll
            for (int mt = 0; mt < 2; ++mt)
                pa[mt] = __builtin_bit_cast(bf16x8,
                         *reinterpret_cast<const u16x8*>(Pw + (mt * 16 + lh) * 72 + ks * 32 + lg * 8));
#pragma unroll
            for (int nt = 0; nt < 4; ++nt) {
                int col = nt * 16 + lh;
                int off = col * 72 + (((ks * 4 + lg) ^ (col >> 3)) << 3);   // u16 units
                vb[nt] = __builtin_bit_cast(bf16x8,
                         *reinterpret_cast<const u16x8*>(&Vt[buf][off]));
            }
#pragma unroll
            for (int mt = 0; mt < 2; ++mt)
#pragma unroll
                for (int nt = 0; nt < 4; ++nt)
                    oa[mt][nt] = mfma16(pa[mt], vb[nt], oa[mt][nt]);
        }
        __builtin_amdgcn_s_setprio(0);
    }

    // ---- final denominators: one 16-lane reduction per row ----
#pragma unroll
    for (int mt = 0; mt < 2; ++mt)
#pragma unroll
        for (int r = 0; r < 4; ++r) {
            float s = lst[mt][r];
#pragma unroll
            for (int o = 1; o < 16; o <<= 1) s += __shfl_xor(s, o);
            lst[mt][r] = 1.0f / s;
        }

    // ---- epilogue: O/l -> ctx (b, s, h*64+a) bf16 ----
#pragma unroll
    for (int mt = 0; mt < 2; ++mt)
#pragma unroll
        for (int nt = 0; nt < 4; ++nt)
#pragma unroll
            for (int r = 0; r < 4; ++r) {
                int row = qt * 128 + wave * 32 + mt * 16 + 4 * lg + r;
                ctx[(size_t)(b * 2048 + row) * 1024 + h * 64 + nt * 16 + lh] =
                    cvt_bf(oa[mt][nt][r] * lst[mt][r]);
            }
}

// ---------------- launch ----------------

extern "C" void kernel_launch(void* const* d_in, const int* in_sizes, int n_in,
                              void* d_out, int out_size, void* d_ws, size_t ws_size,
                              hipStream_t stream)
{
    const float* qs   = (const float*)d_in[0];   // (2,2048,1024)
    const int*   mask = (const int*)d_in[1];     // (2,2048)
    const float* Wqkv = (const float*)d_in[2];   // (1024,3072)
    const float* Wout = (const float*)d_in[3];   // (1024,1024)
    const float* bout = (const float*)d_in[4];   // (1024,)
    float* out = (float*)d_out;                  // (2,2048,1024) fp32

    char* ws = (char*)d_ws;
    u16*   qs_bf = (u16*)(ws);                       //  8,388,608 B
    u16*   WqkvT = (u16*)(ws + 8388608);             //  6,291,456 B (3072x1024)
    u16*   WoutT = (u16*)(ws + 14680064);            //  2,097,152 B (1024x1024)
    u16*   qkvb  = (u16*)(ws + 16777216);            // 25,165,824 B (4096x3072)
    u16*   ctxb  = (u16*)(ws + 41943040);            //  8,388,608 B (4096x1024)
    float* biasb = (float*)(ws + 50331648);          //     16,384 B (4096)

    k_prep<<<8208, 256, 0, stream>>>(qs, qs_bf, mask, biasb, Wqkv, WqkvT, Wout, WoutT);

    k_gemm<128, 128, true, false><<<768, 256, 0, stream>>>(qs_bf, WqkvT, qkvb, nullptr, 4096, 3072, 1024);
    k_attn<<<512, 256, 0, stream>>>(qkvb, biasb, ctxb);
    k_gemm<128, 64, false, true><<<512, 256, 0, stream>>>(ctxb, WoutT, out, bout, 4096, 1024, 1024);
}

// Round 10
// 194.006 us; speedup vs baseline: 1.0039x; 1.0039x over previous
//
#include <hip/hip_runtime.h>
#include <stdint.h>

// MHA fused forward: qs@Wqkv -> flash attention (key mask) -> ctx@Wout + bout
// All matmuls via bf16 MFMA 16x16x32 (fp32 accumulate).

typedef unsigned short u16;
typedef uint32_t u32;
typedef u16   u16x4  __attribute__((ext_vector_type(4)));
typedef u16   u16x8  __attribute__((ext_vector_type(8)));
typedef __bf16 bf16x8 __attribute__((ext_vector_type(8)));
typedef float f32x4  __attribute__((ext_vector_type(4)));

#define DEV __device__ __forceinline__

DEV u16 cvt_bf(float f) {          // native f32->bf16 cast (1 VALU op)
    return __builtin_bit_cast(u16, (__bf16)f);
}

DEV void async16(const void* g, void* l) {   // 16B global->LDS direct (wave-uniform LDS base)
    __builtin_amdgcn_global_load_lds(
        reinterpret_cast<const uint32_t __attribute__((address_space(1)))*>(
            reinterpret_cast<uintptr_t>(g)),
        reinterpret_cast<uint32_t __attribute__((address_space(3)))*>(
            reinterpret_cast<uintptr_t>(l)),
        16, 0, 0);
}

DEV f32x4 mfma16(bf16x8 a, bf16x8 b, f32x4 c) {
    return __builtin_amdgcn_mfma_f32_16x16x32_bf16(a, b, c, 0, 0, 0);
}

// ------- prep (one launch): qs fp32->bf16, mask bias, both weight transposes -------

__global__ void k_prep(const float* __restrict__ qs, u16* __restrict__ qs_bf,
                       const int* __restrict__ m, float* __restrict__ bias,
                       const float* __restrict__ Wqkv, u16* __restrict__ WqkvT,
                       const float* __restrict__ Wout, u16* __restrict__ WoutT) {
    __shared__ float t[32][33];
    int bid = blockIdx.x;
    if (bid < 4096) {                       // qs convert: 4M elems
        int i = (bid * 256 + threadIdx.x) * 4;
        float4 v = *reinterpret_cast<const float4*>(qs + i);
        u16x4 o = { cvt_bf(v.x), cvt_bf(v.y), cvt_bf(v.z), cvt_bf(v.w) };
        *reinterpret_cast<u16x4*>(qs_bf + i) = o;
        return;
    }
    if (bid < 4112) {                       // mask -> additive bias
        int i = (bid - 4096) * 256 + threadIdx.x;
        bias[i] = m[i] ? 0.0f : -1.0e9f;
        return;
    }
    // weight transpose: dst[C x R] = bf16(src[R x C])^T
    const float* src; u16* dst; int R, C, bx, by;
    if (bid < 7184) { int q = bid - 4112; src = Wqkv; dst = WqkvT; R = 1024; C = 3072; bx = q % 96; by = q / 96; }
    else            { int q = bid - 7184; src = Wout; dst = WoutT; R = 1024; C = 1024; bx = q % 32; by = q / 32; }
    int c0 = bx * 32, r0 = by * 32;
    int tx = threadIdx.x & 31, ty = threadIdx.x >> 5;
#pragma unroll
    for (int i = 0; i < 4; ++i)
        t[ty + 8 * i][tx] = src[(size_t)(r0 + ty + 8 * i) * C + c0 + tx];
    __syncthreads();
#pragma unroll
    for (int i = 0; i < 4; ++i)
        dst[(size_t)(c0 + ty + 8 * i) * R + r0 + tx] = cvt_bf(t[tx][ty + 8 * i]);
}

// ---------------- GEMM: C[MxN] = A[MxK] @ Bt[NxK]^T (+bias) ----------------
// BM x BN tile, BK=32, 256 threads = 4 waves (2x2), 64x64 per wave (m97 density).
// TRIPLE-buffered LDS, 2-deep prefetch, raw s_barrier + COUNTED vmcnt (T4):
//   step kt: issue stage(kt+2); ds_read(buf kt); MFMA; vmcnt(SI) [stage(kt+1)
//   done, stage(kt+2) still in flight]; s_barrier.
// Safety: each wave's ds_reads complete before its barrier (compiler lgkmcnt
// before consuming MFMA), so buffer reuse 3 steps later is ordered; vmcnt(SI)
// + barrier proves stage(kt+1) landed for ALL waves. Last 2 iters peeled
// (no new stage in flight -> vmcnt(0) / none).

template <int BM, int BN, bool OUT_BF16, bool HAS_BIAS>
__global__ __launch_bounds__(256, 3) void k_gemm(
    const u16* __restrict__ A, const u16* __restrict__ Bt,
    void* __restrict__ Cv, const float* __restrict__ bias,
    int M, int N, int K)
{
    constexpr int MT = BM / 32, NT = BN / 32;         // frags per wave
    constexpr int SI = BM / 64 + BN / 64;             // async16 per thread per stage
    __shared__ __attribute__((aligned(16))) u16 As[3][BM * 32];
    __shared__ __attribute__((aligned(16))) u16 Bs[3][BN * 32];

    const int tid = threadIdx.x, wave = tid >> 6, lane = tid & 63;
    const int lh = lane & 15, lg = lane >> 4;
    const int nbn = N / BN;

    // bijective XCD swizzle
    const int nwg = gridDim.x;
    const int q8 = nwg >> 3, r8 = nwg & 7;
    const int xcd = blockIdx.x & 7, li = blockIdx.x >> 3;
    const int wg = (xcd < r8 ? xcd * (q8 + 1) : r8 * (q8 + 1) + (xcd - r8) * q8) + li;

    const int m0 = (wg / nbn) * BM, n0 = (wg % nbn) * BN;
    const int wm = wave >> 1, wn = wave & 1;          // 2 x 2 waves
    const int nk = K >> 5;

    auto stage = [&](int buf, int kt) {
#pragma unroll
        for (int i = 0; i < BM / 64; ++i) {           // A: BM*4 chunks of 16B
            int c = i * 256 + tid;
            int row = c >> 2, cc = c & 3;
            int sc = cc ^ (row & 3);                  // pre-swizzled global source
            async16(A + (size_t)(m0 + row) * K + kt * 32 + sc * 8, &As[buf][c * 8]);
        }
#pragma unroll
        for (int i = 0; i < BN / 64; ++i) {           // B: BN*4 chunks
            int c = i * 256 + tid;
            int row = c >> 2, cc = c & 3;
            int sc = cc ^ (row & 3);
            async16(Bt + (size_t)(n0 + row) * K + kt * 32 + sc * 8, &Bs[buf][c * 8]);
        }
    };

    auto waitcnt_si = [&]() {                         // wait: all but newest stage done
        if constexpr (SI == 4) asm volatile("s_waitcnt vmcnt(4)" ::: "memory");
        else                   asm volatile("s_waitcnt vmcnt(3)" ::: "memory");
        __builtin_amdgcn_sched_barrier(0);
    };

    auto compute = [&](int buf) {
        bf16x8 af[MT], bf_[NT];
#pragma unroll
        for (int mt = 0; mt < MT; ++mt) {
            int row = wm * (BM / 2) + mt * 16 + lh;
            int off = row * 32 + ((lg ^ (row & 3)) * 8);           // u16 units
            af[mt] = __builtin_bit_cast(bf16x8,
                     *reinterpret_cast<const u16x8*>(&As[buf][off]));
        }
#pragma unroll
        for (int nt = 0; nt < NT; ++nt) {
            int row = wn * (BN / 2) + nt * 16 + lh;
            int off = row * 32 + ((lg ^ (row & 3)) * 8);
            bf_[nt] = __builtin_bit_cast(bf16x8,
                      *reinterpret_cast<const u16x8*>(&Bs[buf][off]));
        }
        return [=](f32x4 (&acc)[MT][NT]) {
#pragma unroll
            for (int mt = 0; mt < MT; ++mt)
#pragma unroll
                for (int nt = 0; nt < NT; ++nt)
                    acc[mt][nt] = mfma16(af[mt], bf_[nt], acc[mt][nt]);
        };
    };

    f32x4 acc[MT][NT] = {};

    // prologue: 2-deep prefetch
    stage(0, 0);
    stage(1, 1);
    waitcnt_si();                           // stage(0) done; stage(1) in flight
    __builtin_amdgcn_s_barrier();

    // main loop: kt = 0 .. nk-3 (counted vmcnt)
    for (int kt = 0; kt < nk - 2; ++kt) {
        const int buf = kt % 3;
        stage((kt + 2) % 3, kt + 2);
        auto fma = compute(buf);
        __builtin_amdgcn_s_setprio(1);
        fma(acc);
        __builtin_amdgcn_s_setprio(0);
        waitcnt_si();                       // stage(kt+1) done; stage(kt+2) in flight
        __builtin_amdgcn_s_barrier();
    }
    // step nk-2: no new stage; must fully drain for stage(nk-1)
    {
        auto fma = compute((nk - 2) % 3);
        __builtin_amdgcn_s_setprio(1);
        fma(acc);
        __builtin_amdgcn_s_setprio(0);
        asm volatile("s_waitcnt vmcnt(0)" ::: "memory");
        __builtin_amdgcn_sched_barrier(0);
        __builtin_amdgcn_s_barrier();
    }
    // step nk-1: last tile, no sync after
    {
        auto fma = compute((nk - 1) % 3);
        fma(acc);
    }

#pragma unroll
    for (int mt = 0; mt < MT; ++mt)
#pragma unroll
        for (int nt = 0; nt < NT; ++nt) {
            int col = n0 + wn * (BN / 2) + nt * 16 + lh;
#pragma unroll
            for (int r = 0; r < 4; ++r) {
                int row = m0 + wm * (BM / 2) + mt * 16 + 4 * lg + r;   // C/D: row=4*(l>>4)+r
                float v = acc[mt][nt][r];
                if (HAS_BIAS) v += bias[col];
                if (OUT_BF16) ((u16*)Cv)[(size_t)row * N + col] = cvt_bf(v);
                else          ((float*)Cv)[(size_t)row * N + col] = v;
            }
        }
}

// ---------------- flash attention: 4 waves x 32 q-rows (FROZEN from round 9) ----------------
// qkv layout: ((b*2048+s)*48 + c)*64 + a ; c = h (Q), 16+h (K), 32+h (V)
// 512 blocks x 256 threads. KBLK=64. Double-buffered K/V, one barrier per tile.
// No-max softmax (scores bounded, masked -> exp(-1e9)=0).

__global__ __launch_bounds__(256, 3) void k_attn(
    const u16* __restrict__ qkv, const float* __restrict__ biasg, u16* __restrict__ ctx)
{
    __shared__ __attribute__((aligned(16))) u16 Ks[2][64 * 64];   // row-major, src-swizzled chunks
    __shared__ __attribute__((aligned(16))) u16 Vt[2][64 * 72];   // [a][k], k XOR-swizzled by a-group
    __shared__ __attribute__((aligned(16))) u16 Ps[4 * 32 * 72];  // per-wave P (32 rows), stride 72

    const int tid = threadIdx.x, wave = tid >> 6, lane = tid & 63;
    const int lh = lane & 15, lg = lane >> 4;

    const int wg = (blockIdx.x & 7) * 64 + (blockIdx.x >> 3);     // XCD swizzle (512 = 8*64)
    const int qt = wg & 15, bh = wg >> 4;
    const int b = bh >> 4, h = bh & 15;

    const u16* qbase = qkv + ((size_t)b * 2048 * 48 + h) * 64;
    const u16* kbase = qkv + ((size_t)b * 2048 * 48 + 16 + h) * 64;
    const u16* vbase = qkv + ((size_t)b * 2048 * 48 + 32 + h) * 64;
    const float* brow = biasg + b * 2048;

    int srow_[2], scc_[2];
#pragma unroll
    for (int i = 0; i < 2; ++i) {
        int c = (wave * 2 + i) * 64 + lane;
        srow_[i] = c >> 3; scc_[i] = c & 7;
    }

    bf16x8 qf[2][2];
#pragma unroll
    for (int mt = 0; mt < 2; ++mt) {
        int row = qt * 128 + wave * 32 + mt * 16 + lh;
        qf[mt][0] = __builtin_bit_cast(bf16x8,
            *reinterpret_cast<const u16x8*>(qbase + (size_t)row * 3072 + lg * 8));
        qf[mt][1] = __builtin_bit_cast(bf16x8,
            *reinterpret_cast<const u16x8*>(qbase + (size_t)row * 3072 + 32 + lg * 8));
    }

    f32x4 oa[2][4] = {};
    float lst[2][4] = {};

    u16* Pw = &Ps[wave * 32 * 72];

#pragma unroll
    for (int i = 0; i < 2; ++i) {
        int srow = srow_[i], scc = scc_[i];
        async16(kbase + (size_t)srow * 3072 + (scc ^ (srow & 7)) * 8, &Ks[0][(wave * 2 + i) * 512]);
        u16x8 v = *reinterpret_cast<const u16x8*>(vbase + (size_t)srow * 3072 + scc * 8);
#pragma unroll
        for (int j = 0; j < 8; ++j) Vt[0][(scc * 8 + j) * 72 + (srow ^ (scc << 3))] = v[j];
    }

    for (int kt = 0; kt < 32; ++kt) {
        __syncthreads();   // stage(kt) landed (vmcnt/lgkm drain); compute(kt-1) done
        const int buf = kt & 1;
        if (kt + 1 < 32) {
#pragma unroll
            for (int i = 0; i < 2; ++i) {
                int srow = srow_[i], scc = scc_[i];
                async16(kbase + (size_t)((kt + 1) * 64 + srow) * 3072 + (scc ^ (srow & 7)) * 8,
                        &Ks[buf ^ 1][(wave * 2 + i) * 512]);
                u16x8 v = *reinterpret_cast<const u16x8*>(
                    vbase + (size_t)((kt + 1) * 64 + srow) * 3072 + scc * 8);
#pragma unroll
                for (int j = 0; j < 8; ++j)
                    Vt[buf ^ 1][(scc * 8 + j) * 72 + (srow ^ (scc << 3))] = v[j];
            }
        }

        float biasv[4];
#pragma unroll
        for (int nt = 0; nt < 4; ++nt) biasv[nt] = brow[kt * 64 + nt * 16 + lh];

        // ---- S = Q K^T (per wave: 32 x 64); kb shared across both m-frags ----
        f32x4 sa[2][4] = {};
        __builtin_amdgcn_s_setprio(1);
#pragma unroll
        for (int ks = 0; ks < 2; ++ks) {
            bf16x8 kb[4];
#pragma unroll
            for (int nt = 0; nt < 4; ++nt) {
                int row = nt * 16 + lh;
                int off = row * 64 + (((ks * 4 + lg) ^ (row & 7)) << 3);   // u16 units
                kb[nt] = __builtin_bit_cast(bf16x8,
                         *reinterpret_cast<const u16x8*>(&Ks[buf][off]));
            }
#pragma unroll
            for (int mt = 0; mt < 2; ++mt)
#pragma unroll
                for (int nt = 0; nt < 4; ++nt)
                    sa[mt][nt] = mfma16(qf[mt][ks], kb[nt], sa[mt][nt]);
        }
        __builtin_amdgcn_s_setprio(0);

        // ---- no-max softmax: e = __expf(fma(s, 0.125, bias)) — native v_exp path ----
#pragma unroll
        for (int mt = 0; mt < 2; ++mt)
#pragma unroll
            for (int nt = 0; nt < 4; ++nt)
#pragma unroll
                for (int r = 0; r < 4; ++r) {
                    float e = __expf(fmaf(sa[mt][nt][r], 0.125f, biasv[nt]));
                    lst[mt][r] += e;
                    Pw[(mt * 16 + 4 * lg + r) * 72 + nt * 16 + lh] = cvt_bf(e);  // D-layout write
                }

        // ---- O += P V ; vb shared across both m-frags ----
        __builtin_amdgcn_s_setprio(1);
#pragma unroll
        for (int ks = 0; ks < 2; ++ks) {
            bf16x8 pa[2], vb[4];
#pragma unroll
            for (int mt = 0; mt < 2; ++mt)
                pa[mt] = __builtin_bit_cast(bf16x8,
                         *reinterpret_cast<const u16x8*>(Pw + (mt * 16 + lh) * 72 + ks * 32 + lg * 8));
#pragma unroll
            for (int nt = 0; nt < 4; ++nt) {
                int col = nt * 16 + lh;
                int off = col * 72 + (((ks * 4 + lg) ^ (col >> 3)) << 3);   // u16 units
                vb[nt] = __builtin_bit_cast(bf16x8,
                         *reinterpret_cast<const u16x8*>(&Vt[buf][off]));
            }
#pragma unroll
            for (int mt = 0; mt < 2; ++mt)
#pragma unroll
                for (int nt = 0; nt < 4; ++nt)
                    oa[mt][nt] = mfma16(pa[mt], vb[nt], oa[mt][nt]);
        }
        __builtin_amdgcn_s_setprio(0);
    }

    // ---- final denominators: one 16-lane reduction per row ----
#pragma unroll
    for (int mt = 0; mt < 2; ++mt)
#pragma unroll
        for (int r = 0; r < 4; ++r) {
            float s = lst[mt][r];
#pragma unroll
            for (int o = 1; o < 16; o <<= 1) s += __shfl_xor(s, o);
            lst[mt][r] = 1.0f / s;
        }

    // ---- epilogue: O/l -> ctx (b, s, h*64+a) bf16 ----
#pragma unroll
    for (int mt = 0; mt < 2; ++mt)
#pragma unroll
        for (int nt = 0; nt < 4; ++nt)
#pragma unroll
            for (int r = 0; r < 4; ++r) {
                int row = qt * 128 + wave * 32 + mt * 16 + 4 * lg + r;
                ctx[(size_t)(b * 2048 + row) * 1024 + h * 64 + nt * 16 + lh] =
                    cvt_bf(oa[mt][nt][r] * lst[mt][r]);
            }
}

// ---------------- launch ----------------

extern "C" void kernel_launch(void* const* d_in, const int* in_sizes, int n_in,
                              void* d_out, int out_size, void* d_ws, size_t ws_size,
                              hipStream_t stream)
{
    const float* qs   = (const float*)d_in[0];   // (2,2048,1024)
    const int*   mask = (const int*)d_in[1];     // (2,2048)
    const float* Wqkv = (const float*)d_in[2];   // (1024,3072)
    const float* Wout = (const float*)d_in[3];   // (1024,1024)
    const float* bout = (const float*)d_in[4];   // (1024,)
    float* out = (float*)d_out;                  // (2,2048,1024) fp32

    char* ws = (char*)d_ws;
    u16*   qs_bf = (u16*)(ws);                       //  8,388,608 B
    u16*   WqkvT = (u16*)(ws + 8388608);             //  6,291,456 B (3072x1024)
    u16*   WoutT = (u16*)(ws + 14680064);            //  2,097,152 B (1024x1024)
    u16*   qkvb  = (u16*)(ws + 16777216);            // 25,165,824 B (4096x3072)
    u16*   ctxb  = (u16*)(ws + 41943040);            //  8,388,608 B (4096x1024)
    float* biasb = (float*)(ws + 50331648);          //     16,384 B (4096)

    k_prep<<<8208, 256, 0, stream>>>(qs, qs_bf, mask, biasb, Wqkv, WqkvT, Wout, WoutT);

    k_gemm<128, 128, true, false><<<768, 256, 0, stream>>>(qs_bf, WqkvT, qkvb, nullptr, 4096, 3072, 1024);
    k_attn<<<512, 256, 0, stream>>>(qkvb, biasb, ctxb);
    k_gemm<128, 64, false, true><<<512, 256, 0, stream>>>(ctxb, WoutT, out, bout, 4096, 1024, 1024);
}